// Round 8
// baseline (21.402 us; speedup 1.0000x reference)
//
#include <hip/hip_runtime.h>

typedef unsigned long long ull;
#define NT 100

// Lock-free min-root union-find in LDS. Parent strictly decreases along
// chains -> termination, no cycles.
__device__ __forceinline__ int find_root(int* P, int x) {
    int p = P[x];
    while (p != x) {
        int gp = P[p];
        P[x] = gp;          // benign racy path-halving (gp is an ancestor, gp < x)
        x = gp;
        p = P[x];
    }
    return x;
}

// Returns 1 iff this call performed the hook (merged two distinct trees).
// Per-block total of successful hooks == components merged (schedule-invariant).
__device__ __forceinline__ int unite(int* P, int a, int b) {
    a = find_root(P, a);
    b = find_root(P, b);
    while (a != b) {
        if (a < b) { int t = a; a = b; b = t; }   // hook larger under smaller
        int old = atomicCAS(&P[a], a, b);
        if (old == a) return 1;
        a = find_root(P, old);
        b = find_root(P, b);
    }
    return 0;
}

// One 512-thread block per (b, c, t). Wave h (0..7) owns column strip
// [8h, 8h+8); lane r of wave h owns row r of that strip (8-bit mask).
// Run id = ((h*4 + k) << 6) | row,  k < 4 (max 4 runs per 8 cols).
// Per-wave packed partial {px|eh|ev|nruns|merges} -> ws[bid*8 + h].
__global__ __launch_bounds__(512)
void betti_partial(const float* __restrict__ prob,   // [8,3,64,64]
                   ull* __restrict__ ws)             // [1600*8]
{
    __shared__ int P[2048];
    __shared__ int bL[7][64];                 // run id at col 8h+7, or -1
    __shared__ int bR[7][64];                 // run id at col 8(h+1), or -1

    const int bid = blockIdx.x;               // (b*2 + c)*100 + t
    const int t   = bid % NT;
    const int cb  = bid / NT;

    const float thr = (float)t * (1.0f / 99.0f);
    const float* img = prob + (size_t)((cb >> 1) * 3 + (cb & 1)) * 4096;

    const int tid  = threadIdx.x;
    const int h    = tid >> 6;                // wave = column strip
    const int lane = tid & 63;                // row

    // ---- load row `lane`, cols 8h..8h+7 (2 x float4), build 8-bit mask ----
    const float4* rp = (const float4*)(img + (lane << 6) + (h << 3));
    unsigned int m = 0;
    #pragma unroll
    for (int q = 0; q < 2; ++q) {
        float4 v = rp[q];
        m |= (unsigned)(v.x > thr) << (4 * q + 0);
        m |= (unsigned)(v.y > thr) << (4 * q + 1);
        m |= (unsigned)(v.z > thr) << (4 * q + 2);
        m |= (unsigned)(v.w > thr) << (4 * q + 3);
    }

    // ---- init my 4 UF slots (only my wave touches them pre-barrier) ----
    #pragma unroll
    for (int k = 0; k < 4; ++k) {
        int s = ((h * 4 + k) << 6) | lane;
        P[s] = s;
    }

    const unsigned um = m & 0xFFu;
    unsigned up        = (unsigned)__shfl_up((int)um, 1, 64);
    unsigned starts    = um & ~(um << 1) & 0xFFu;         // run starts
    unsigned starts_up = (unsigned)__shfl_up((int)starts, 1, 64);
    if (lane == 0) { up = 0u; starts_up = 0u; }

    const int px    = __popc(um);
    int       eh    = __popc(um & (um >> 1));             // horiz edges in strip
    const int ev    = __popc(um & up);                    // vert edges in strip
    const int nruns = __popc(starts);

    // ---- boundary descriptors (written pre-barrier, read post-barrier) ----
    if (h < 7)   // run containing col 8h+7 is the last-starting run: nruns-1
        bL[h][lane] = ((um >> 7) & 1u) ? (((h * 4 + (nruns - 1)) << 6) | lane) : -1;
    if (h > 0)   // if col 8h is set, it is a run start: index 0
        bR[h - 1][lane] = (um & 1u) ? (((h * 4) << 6) | lane) : -1;

    // ---- within-strip vertical-overlap unions (own slots only: no barrier) ----
    int merges = 0;
    unsigned ov = um & up;
    unsigned ss = ov & ~(ov << 1) & 0xFFu;                // segment starts
    while (ss) {
        int j = __ffs(ss) - 1;
        ss &= ss - 1;
        unsigned le = (2u << j) - 1;                      // bits [0..j]
        int kc = __popc(starts    & le) - 1;
        int ku = __popc(starts_up & le) - 1;
        merges += unite(P, ((h * 4 + kc) << 6) | lane, ((h * 4 + ku) << 6) | (lane - 1));
    }

    __syncthreads();   // all inits + bL/bR + (disjoint) within-unions visible

    // ---- boundary unions + crossing horizontal edges (waves 0..6) ----
    if (h < 7) {
        int l = bL[h][lane], r = bR[h][lane];
        if (l >= 0 && r >= 0) { eh++; merges += unite(P, l, r); }
    }

    // ---- packed {px(13)|eh(12)|ev(12)|nruns(12)|merges(12)} wave reduce ----
    // block totals: px<=4096, eh<=4032, ev<=4032, nruns<=2048, merges<2048
    ull pk = (ull)px
           | ((ull)eh     << 13)
           | ((ull)ev     << 25)
           | ((ull)nruns  << 37)
           | ((ull)merges << 49);
    #pragma unroll
    for (int o = 32; o > 0; o >>= 1)
        pk += __shfl_down(pk, o, 64);

    if (lane == 0) ws[(size_t)bid * 8 + h] = pk;          // plain store
}

// 8 blocks: block b combines 200 (c,t) tiles' 8 wave-partials each,
// does the betti math + gt |diff|, plain-stores out[b].
__global__ __launch_bounds__(256)
void betti_final(const ull* __restrict__ ws,
                 const int* __restrict__ gt,              // [8,3,100,2]
                 float* __restrict__ out)                 // [8]
{
    __shared__ int wsum[4];
    const int b = blockIdx.x;
    const int tid = threadIdx.x;

    int contrib = 0;
    if (tid < 200) {                                      // tid = c*100 + t
        const ull* p = ws + (size_t)(b * 200 + tid) * 8;
        ull s = 0;
        #pragma unroll
        for (int k = 0; k < 8; ++k) s += p[k];
        const int px = (int)( s        & 0x1FFF);
        const int eh = (int)((s >> 13) & 0xFFF);
        const int ev = (int)((s >> 25) & 0xFFF);
        const int nr = (int)((s >> 37) & 0xFFF);
        const int mg = (int)((s >> 49) & 0xFFF);
        const int b0 = nr - mg;
        const int b1 = b0 - (px - (eh + ev));

        const int c = tid / 100;
        const int t = tid - c * 100;
        int d;
        if (c == 0) {
            const int* g0 = gt + (((size_t)b * 3 + 0) * NT + t) * 2;
            const int* g2 = gt + (((size_t)b * 3 + 2) * NT + t) * 2;
            d = b0 - g0[0]; contrib += d < 0 ? -d : d;
            d = b1 - g0[1]; contrib += d < 0 ? -d : d;
            d = b0 - g2[0]; contrib += d < 0 ? -d : d;
            d = b1 - g2[1]; contrib += d < 0 ? -d : d;
        } else {
            const int* g1 = gt + (((size_t)b * 3 + 1) * NT + t) * 2;
            d = b0 - g1[0]; contrib += d < 0 ? -d : d;
            d = b1 - g1[1]; contrib += d < 0 ? -d : d;
        }
    }

    #pragma unroll
    for (int o = 32; o > 0; o >>= 1) contrib += __shfl_down(contrib, o, 64);
    if ((tid & 63) == 0) wsum[tid >> 6] = contrib;
    __syncthreads();
    if (tid == 0)
        out[b] = (float)(wsum[0] + wsum[1] + wsum[2] + wsum[3]);
}

extern "C" void kernel_launch(void* const* d_in, const int* in_sizes, int n_in,
                              void* d_out, int out_size, void* d_ws, size_t ws_size,
                              hipStream_t stream) {
    const float* prob = (const float*)d_in[0];   // [8,3,64,64] f32
    const int*   gt   = (const int*)d_in[1];     // [8,3,100,2] i32
    float* out = (float*)d_out;                  // [8] f32
    ull* ws = (ull*)d_ws;                        // 1600*8 u64 scratch

    const int nblocks = 8 * 2 * NT;   // 1600 blocks, one per (b,c,t)
    betti_partial<<<nblocks, 512, 0, stream>>>(prob, ws);
    betti_final<<<8, 256, 0, stream>>>(ws, gt, out);
}